// Round 5
// baseline (157.990 us; speedup 1.0000x reference)
//
#include <hip/hip_runtime.h>

#define NB      16
#define T_IN    2048
#define OUT_LEN 4096
#define D       384
#define D4      (D / 4)   // 96 float4 per row

typedef float f32x4 __attribute__((ext_vector_type(4)));

// ---------------------------------------------------------------------------
// Kernel 1: per-batch inclusive cumsum of repeat_count (2048 int32/batch).
// One block per batch, 256 threads x 8 elements. Also emits seq_len (= last
// cumsum value) as FLOAT into the tail of d_out (output 1 of the tuple).
// ---------------------------------------------------------------------------
__global__ __launch_bounds__(256) void cumsum_kernel(const int* __restrict__ r,
                                                     int* __restrict__ cum,
                                                     float* __restrict__ seqlen_out) {
    const int b   = blockIdx.x;
    const int tid = threadIdx.x;
    const int4* rb = (const int4*)(r + b * T_IN);
    int4*       cb = (int4*)(cum + b * T_IN);

    int4 v0 = rb[tid * 2];
    int4 v1 = rb[tid * 2 + 1];
    int v[8] = {v0.x, v0.y, v0.z, v0.w, v1.x, v1.y, v1.z, v1.w};

    int s = 0;
#pragma unroll
    for (int i = 0; i < 8; ++i) { s += v[i]; v[i] = s; }

    // inclusive wave scan (wave = 64) of per-thread totals
    const int lane = tid & 63;
    const int wid  = tid >> 6;
    int pre = s;
#pragma unroll
    for (int off = 1; off < 64; off <<= 1) {
        int up = __shfl_up(pre, off, 64);
        if (lane >= off) pre += up;
    }

    __shared__ int wsum[4];
    if (lane == 63) wsum[wid] = pre;
    __syncthreads();

    int excl = pre - s;               // exclusive prefix within wave
    for (int w = 0; w < wid; ++w) excl += wsum[w];

#pragma unroll
    for (int i = 0; i < 8; ++i) v[i] += excl;

    cb[tid * 2]     = make_int4(v[0], v[1], v[2], v[3]);
    cb[tid * 2 + 1] = make_int4(v[4], v[5], v[6], v[7]);

    if (tid == 255) seqlen_out[b] = (float)v[7];
}

// ---------------------------------------------------------------------------
// Kernel 2 (fused search + gather): each block = 8 output rows.
// Threads 0..7 binary-search the L2-resident cumsum for their row's input
// index (or -1 if past seq_len) into LDS; then all 256 threads gather
// 8 rows x 96 float4 (3 chunks of 256) with coalesced reads and
// nontemporal coalesced writes. idx < 0 -> zeros (valid-mask + poison).
// ---------------------------------------------------------------------------
__global__ __launch_bounds__(256) void regulate_kernel(const f32x4* __restrict__ x,
                                                       const int* __restrict__ cum,
                                                       f32x4* __restrict__ out) {
    const unsigned row0 = blockIdx.x * 8u;                // first output row
    const unsigned b    = row0 >> 12;                     // row0 / OUT_LEN
    const int* cb = cum + b * T_IN;

    __shared__ int sidx[8];
    if (threadIdx.x < 8) {
        const int t   = (int)(row0 & (OUT_LEN - 1)) + (int)threadIdx.x;
        const int seq = cb[T_IN - 1];
        int res = -1;
        if (t < seq) {
            int lo = 0, hi = T_IN;
            while (lo < hi) {
                int mid = (lo + hi) >> 1;
                if (cb[mid] <= t) lo = mid + 1; else hi = mid;
            }
            res = lo < (T_IN - 1) ? lo : (T_IN - 1);
        }
        sidx[threadIdx.x] = res;
    }
    __syncthreads();

    const f32x4*  xb   = x + (size_t)b * T_IN * D4;
    const unsigned base = row0 * (unsigned)D4;

#pragma unroll
    for (int k = 0; k < 3; ++k) {
        const unsigned local = threadIdx.x + k * 256u;    // 0..767
        const unsigned rloc  = local / D4;                // const-96 divide
        const unsigned d     = local - rloc * D4;
        const int irow = sidx[rloc];
        f32x4 val = (f32x4)(0.f);
        if (irow >= 0) val = xb[(unsigned)irow * D4 + d];
        __builtin_nontemporal_store(val, &out[base + local]);
    }
}

extern "C" void kernel_launch(void* const* d_in, const int* in_sizes, int n_in,
                              void* d_out, int out_size, void* d_ws, size_t ws_size,
                              hipStream_t stream) {
    const float* x  = (const float*)d_in[0];
    const int*   rc = (const int*)d_in[1];
    // d_in[2] = output_max_seq_len scalar (4096), compiled in.

    float* out        = (float*)d_out;
    float* seqlen_out = out + (size_t)NB * OUT_LEN * D;  // tail: output 1

    int* cum = (int*)d_ws;                 // NB*T_IN ints = 128 KB

    cumsum_kernel<<<NB, 256, 0, stream>>>(rc, cum, seqlen_out);

    const unsigned n_rows = (unsigned)NB * OUT_LEN;        // 65536 rows
    regulate_kernel<<<n_rows / 8, 256, 0, stream>>>((const f32x4*)x, cum,
                                                    (f32x4*)out);
}

// Round 6
// 144.045 us; speedup vs baseline: 1.0968x; 1.0968x over previous
//
#include <hip/hip_runtime.h>

#define NB      16
#define T_IN    2048
#define OUT_LEN 4096
#define D       384
#define D4      (D / 4)   // 96 float4 per row

typedef float f32x4 __attribute__((ext_vector_type(4)));

// ---------------------------------------------------------------------------
// Single fused kernel. Each block owns 8 output rows of one batch.
//  Phase 1: block recomputes the batch's full cumsum (2048 int32, 8 KB,
//           L2-resident r) into LDS: thread-local scan of 8 + wave shfl scan
//           + cross-wave LDS combine. Redundant across blocks but costs
//           ~2 us aggregate in L2 BW — cheaper than a separate kernel launch
//           + dependency bubble + ws round-trip.
//  Phase 2: threads 0..7 binary-search LDS cumsum for their row's input
//           index (-1 when t >= seq_len).
//  Phase 3: 256 threads gather 8 rows x 96 float4 (3 coalesced chunks),
//           zeros for invalid rows (covers the 0xAA poison).
// seq_len (output 1, as float) is written by the first block of each batch.
// ---------------------------------------------------------------------------
__global__ __launch_bounds__(256) void lenreg_kernel(const f32x4* __restrict__ x,
                                                     const int* __restrict__ r,
                                                     f32x4* __restrict__ out,
                                                     float* __restrict__ seqlen_out) {
    __shared__ int scum[T_IN];   // 8 KB
    __shared__ int wsum[4];
    __shared__ int sidx[8];

    const unsigned row0 = blockIdx.x * 8u;     // first output row (global)
    const unsigned b    = row0 >> 12;          // row0 / OUT_LEN
    const int tid = threadIdx.x;

    // ---- Phase 1: per-block cumsum into LDS ----
    const int4* rb = (const int4*)(r + b * T_IN);
    int4 v0 = rb[tid * 2];
    int4 v1 = rb[tid * 2 + 1];
    int v[8] = {v0.x, v0.y, v0.z, v0.w, v1.x, v1.y, v1.z, v1.w};

    int s = 0;
#pragma unroll
    for (int i = 0; i < 8; ++i) { s += v[i]; v[i] = s; }

    const int lane = tid & 63;
    const int wid  = tid >> 6;
    int pre = s;
#pragma unroll
    for (int off = 1; off < 64; off <<= 1) {
        int up = __shfl_up(pre, off, 64);
        if (lane >= off) pre += up;
    }
    if (lane == 63) wsum[wid] = pre;
    __syncthreads();

    int excl = pre - s;                        // exclusive prefix within wave
    for (int w = 0; w < wid; ++w) excl += wsum[w];
#pragma unroll
    for (int i = 0; i < 8; ++i) v[i] += excl;

    ((int4*)scum)[tid * 2]     = make_int4(v[0], v[1], v[2], v[3]);
    ((int4*)scum)[tid * 2 + 1] = make_int4(v[4], v[5], v[6], v[7]);
    __syncthreads();

    // ---- Phase 2: binary search for this block's 8 rows ----
    const int seq = scum[T_IN - 1];            // broadcast read
    if (tid < 8) {
        const int t = (int)(row0 & (OUT_LEN - 1)) + tid;
        int res = -1;
        if (t < seq) {
            int lo = 0, hi = T_IN;
            while (lo < hi) {
                int mid = (lo + hi) >> 1;
                if (scum[mid] <= t) lo = mid + 1; else hi = mid;
            }
            res = lo < (T_IN - 1) ? lo : (T_IN - 1);
        }
        sidx[tid] = res;
    }
    if (tid == 0 && (row0 & (OUT_LEN - 1)) == 0)
        seqlen_out[b] = (float)seq;            // output 1 (float)
    __syncthreads();

    // ---- Phase 3: gather 8 rows x 96 float4, coalesced ----
    const f32x4*  xb   = x + (size_t)b * T_IN * D4;
    const unsigned base = row0 * (unsigned)D4;

#pragma unroll
    for (int k = 0; k < 3; ++k) {
        const unsigned local = (unsigned)tid + k * 256u;  // 0..767
        const unsigned rloc  = local / D4;                // const-96 divide
        const unsigned d     = local - rloc * D4;
        const int irow = sidx[rloc];
        f32x4 val = (f32x4)(0.f);
        if (irow >= 0) val = xb[(unsigned)irow * D4 + d];
        out[base + local] = val;
    }
}

extern "C" void kernel_launch(void* const* d_in, const int* in_sizes, int n_in,
                              void* d_out, int out_size, void* d_ws, size_t ws_size,
                              hipStream_t stream) {
    const float* x  = (const float*)d_in[0];
    const int*   rc = (const int*)d_in[1];
    // d_in[2] = output_max_seq_len scalar (4096), compiled in.

    float* out        = (float*)d_out;
    float* seqlen_out = out + (size_t)NB * OUT_LEN * D;  // tail: output 1

    const unsigned n_rows = (unsigned)NB * OUT_LEN;      // 65536 rows
    lenreg_kernel<<<n_rows / 8, 256, 0, stream>>>((const f32x4*)x, rc,
                                                  (f32x4*)out, seqlen_out);
}